// Round 2
// baseline (648.416 us; speedup 1.0000x reference)
//
#include <hip/hip_runtime.h>

// Problem constants (fixed by setup_inputs)
constexpr int NB = 4;
constexpr int NI = 512;
constexpr int NK = 512;
constexpr int NC = 64;
constexpr float LN_EPS = 1e-5f;

// DIAGNOSTIC BUILD: k_S and k_Va repeat their main loops 4x (averaged with
// 0.25f) to push their durations above the 158us harness-fill floor so they
// appear in the rocprof top-5 with real counters. Base = round-0 438us kernel.
constexpr int REP = 4;

// ---------------------------------------------------------------------------
// k_S: S[b,k,c] = sum_i exp(z[b,i,k,c]) * (z_mask[b,i,k] + 1e-6)
// grid = B * (K/16) * 8 i-chunks, block = 256 (16 k x 16 float4-of-c)
// ---------------------------------------------------------------------------
__global__ __launch_bounds__(256) void k_S(const float* __restrict__ z,
                                           const float* __restrict__ zmask,
                                           float* __restrict__ S) {
    int idx = blockIdx.x;
    int ic = idx & 7;  idx >>= 3;   // i-chunk 0..7
    int kt = idx & 31; int b = idx >> 5;
    int tid = threadIdx.x;
    int kk = tid >> 4;              // 0..15
    int c4 = tid & 15;              // 0..15
    int k = kt * 16 + kk;

    float4 acc = make_float4(0.f, 0.f, 0.f, 0.f);
    for (int rep = 0; rep < REP; ++rep) {
        float4 a = make_float4(0.f, 0.f, 0.f, 0.f);
        for (int ii = 0; ii < NI / 8; ++ii) {
            int i = ic * (NI / 8) + ii;
            size_t row = ((size_t)(b * NI + i) * NK + k) * NC;
            const float4 zv = *(const float4*)(z + row + c4 * 4);
            float m = zmask[(size_t)(b * NI + i) * NK + k] + 1e-6f;
            a.x += __expf(zv.x) * m;
            a.y += __expf(zv.y) * m;
            a.z += __expf(zv.z) * m;
            a.w += __expf(zv.w) * m;
        }
        acc.x += 0.25f * a.x;
        acc.y += 0.25f * a.y;
        acc.z += 0.25f * a.z;
        acc.w += 0.25f * a.w;
    }
    float* sp = S + (size_t)(b * NK + k) * NC + c4 * 4;
    atomicAdd(sp + 0, acc.x);
    atomicAdd(sp + 1, acc.y);
    atomicAdd(sp + 2, acc.z);
    atomicAdd(sp + 3, acc.w);
}

// ---------------------------------------------------------------------------
// k_R: R[b,k,c] = (dot(Q[b,k,:], W1[c,:]) + b1[c]) / S[b,k,c]
// grid = B*K blocks of 64 threads (one per c)
// ---------------------------------------------------------------------------
__global__ __launch_bounds__(64) void k_R(const float* __restrict__ Q,
                                          const float* __restrict__ W1,
                                          const float* __restrict__ b1,
                                          const float* __restrict__ S,
                                          float* __restrict__ R) {
    int bk = blockIdx.x;
    int c = threadIdx.x;
    __shared__ float q[NC];
    q[c] = Q[(size_t)bk * NC + c];
    __syncthreads();
    const float* w = W1 + c * NC;
    float acc = b1[c];
#pragma unroll
    for (int j = 0; j < NC; ++j) acc += q[j] * w[j];
    R[(size_t)bk * NC + c] = acc / S[(size_t)bk * NC + c];
}

// ---------------------------------------------------------------------------
// k_Va: Va[b,i,c] = sum_k mask*(mask+1e-6)*exp(z[b,i,k,c]) * R[b,k,c]
// grid = B*I blocks, block = 256 (16 k-stripes x 16 float4-of-c)
// Also emits per-(b,i) partial (sum, sumsq) for LN1.
// ---------------------------------------------------------------------------
__global__ __launch_bounds__(256) void k_Va(const float* __restrict__ z,
                                            const float* __restrict__ zmask,
                                            const float* __restrict__ R,
                                            float* __restrict__ Va,
                                            float* __restrict__ part1) {
    int bi = blockIdx.x;
    int b = bi >> 9;                 // / NI
    int tid = threadIdx.x;
    int kk = tid >> 4;
    int c4 = tid & 15;

    const float* zrow = z + (size_t)bi * NK * NC;
    const float* mrow = zmask + (size_t)bi * NK;
    const float* Rb = R + (size_t)b * NK * NC;

    float4 acc = make_float4(0.f, 0.f, 0.f, 0.f);
    for (int rep = 0; rep < REP; ++rep) {
        float4 a = make_float4(0.f, 0.f, 0.f, 0.f);
        for (int kb = 0; kb < NK / 16; ++kb) {
            int k = kb * 16 + kk;
            const float4 zv = *(const float4*)(zrow + (size_t)k * NC + c4 * 4);
            const float4 rv = *(const float4*)(Rb + (size_t)k * NC + c4 * 4);
            float zm = mrow[k];
            float m2 = zm * (zm + 1e-6f);
            a.x += __expf(zv.x) * m2 * rv.x;
            a.y += __expf(zv.y) * m2 * rv.y;
            a.z += __expf(zv.z) * m2 * rv.z;
            a.w += __expf(zv.w) * m2 * rv.w;
        }
        acc.x += 0.25f * a.x;
        acc.y += 0.25f * a.y;
        acc.z += 0.25f * a.z;
        acc.w += 0.25f * a.w;
    }

    __shared__ float4 part[256];
    part[tid] = acc;
    __syncthreads();
    // reduce across the 16 kk-stripes (tid = kk*16 + c4)
    for (int s = 128; s >= 16; s >>= 1) {
        if (tid < s) {
            float4 o = part[tid + s];
            float4 m = part[tid];
            m.x += o.x; m.y += o.y; m.z += o.z; m.w += o.w;
            part[tid] = m;
        }
        __syncthreads();
    }
    __shared__ float red[32];
    if (tid < 16) {
        float4 v = part[tid];
        *(float4*)(Va + (size_t)bi * NC + tid * 4) = v;
        red[tid]      = v.x + v.y + v.z + v.w;
        red[16 + tid] = v.x * v.x + v.y * v.y + v.z * v.z + v.w * v.w;
    }
    __syncthreads();
    if (tid == 0) {
        float s0 = 0.f, s1 = 0.f;
        for (int t = 0; t < 16; ++t) { s0 += red[t]; s1 += red[16 + t]; }
        part1[bi * 2]     = s0;
        part1[bi * 2 + 1] = s1;
    }
}

// ---------------------------------------------------------------------------
// k_red: per-batch reduce of (sum, sumsq) partials -> stats[b*2], stats[b*2+1]
// grid = B, block = 256
// ---------------------------------------------------------------------------
__global__ __launch_bounds__(256) void k_red(const float* __restrict__ part,
                                             float* __restrict__ stats) {
    int b = blockIdx.x;
    int tid = threadIdx.x;
    float s0 = 0.f, s1 = 0.f;
    for (int i = tid; i < NI; i += 256) {
        int bi = b * NI + i;
        s0 += part[bi * 2];
        s1 += part[bi * 2 + 1];
    }
    __shared__ float l0[256], l1[256];
    l0[tid] = s0; l1[tid] = s1;
    __syncthreads();
    for (int s = 128; s; s >>= 1) {
        if (tid < s) { l0[tid] += l0[tid + s]; l1[tid] += l1[tid + s]; }
        __syncthreads();
    }
    if (tid == 0) { stats[b * 2] = l0[0]; stats[b * 2 + 1] = l1[0]; }
}

// ---------------------------------------------------------------------------
// k_Y: Y[b,i,c] = V + (LN1(Va) @ W2^T + b2); emits LN2 partials per (b,i)
// grid = B*I, block = 64 (one wave)
// ---------------------------------------------------------------------------
__global__ __launch_bounds__(64) void k_Y(const float* __restrict__ V,
                                          const float* __restrict__ W2,
                                          const float* __restrict__ b2,
                                          const float* __restrict__ Va,
                                          const float* __restrict__ stats1,
                                          float* __restrict__ Y,
                                          float* __restrict__ part2) {
    int bi = blockIdx.x;
    int b = bi >> 9;
    int c = threadIdx.x;
    const float n = (float)(NI * NC);
    float mu = stats1[b * 2] / n;
    float var = stats1[b * 2 + 1] / n - mu * mu;
    float rstd = rsqrtf(var + LN_EPS);

    __shared__ float xn[NC];
    xn[c] = (Va[(size_t)bi * NC + c] - mu) * rstd;
    __syncthreads();

    const float* w = W2 + c * NC;
    float acc = b2[c];
#pragma unroll
    for (int j = 0; j < NC; ++j) acc += xn[j] * w[j];
    float y = V[(size_t)bi * NC + c] + acc;
    Y[(size_t)bi * NC + c] = y;

    float s0 = y, s1 = y * y;
    for (int off = 32; off; off >>= 1) {
        s0 += __shfl_down(s0, off);
        s1 += __shfl_down(s1, off);
    }
    if (c == 0) { part2[bi * 2] = s0; part2[bi * 2 + 1] = s1; }
}

// ---------------------------------------------------------------------------
// k_out: out = LN2(Y), elementwise with per-b stats
// ---------------------------------------------------------------------------
__global__ __launch_bounds__(256) void k_out(const float* __restrict__ Y,
                                             const float* __restrict__ stats2,
                                             float* __restrict__ out) {
    int idx = blockIdx.x * 256 + threadIdx.x;
    int b = idx >> 15;               // / (NI*NC)
    const float n = (float)(NI * NC);
    float mu = stats2[b * 2] / n;
    float var = stats2[b * 2 + 1] / n - mu * mu;
    float rstd = rsqrtf(var + LN_EPS);
    out[idx] = (Y[idx] - mu) * rstd;
}

// ---------------------------------------------------------------------------
extern "C" void kernel_launch(void* const* d_in, const int* in_sizes, int n_in,
                              void* d_out, int out_size, void* d_ws, size_t ws_size,
                              hipStream_t stream) {
    const float* V  = (const float*)d_in[0];
    const float* Q  = (const float*)d_in[1];
    const float* z  = (const float*)d_in[2];
    const float* zm = (const float*)d_in[3];
    const float* W1 = (const float*)d_in[4];
    const float* b1 = (const float*)d_in[5];
    const float* W2 = (const float*)d_in[6];
    const float* b2 = (const float*)d_in[7];
    // d_in[8] is dim == 1 (fixed by setup_inputs)

    float* ws     = (float*)d_ws;
    float* S      = ws;                         // 131072
    float* R      = ws + 131072;                // 131072
    float* Va     = ws + 262144;                // 131072
    float* Y      = ws + 393216;                // 131072
    float* part1  = ws + 524288;                // 4096
    float* part2  = ws + 528384;                // 4096
    float* stats1 = ws + 532480;                // 8
    float* stats2 = ws + 532488;                // 8

    hipMemsetAsync(S, 0, 131072 * sizeof(float), stream);

    k_S  <<<NB * (NK / 16) * 8, 256, 0, stream>>>(z, zm, S);
    k_R  <<<NB * NK,            64,  0, stream>>>(Q, W1, b1, S, R);
    k_Va <<<NB * NI,            256, 0, stream>>>(z, zm, R, Va, part1);
    k_red<<<NB,                 256, 0, stream>>>(part1, stats1);
    k_Y  <<<NB * NI,            64,  0, stream>>>(V, W2, b2, Va, stats1, Y, part2);
    k_red<<<NB,                 256, 0, stream>>>(part2, stats2);
    k_out<<<(NB * NI * NC) / 256, 256, 0, stream>>>(Y, stats2, (float*)d_out);
}

// Round 3
// 440.642 us; speedup vs baseline: 1.4715x; 1.4715x over previous
//
#include <hip/hip_runtime.h>

// Problem constants (fixed by setup_inputs)
constexpr int NB = 4;
constexpr int NI = 512;
constexpr int NK = 512;
constexpr int NC = 64;
constexpr float LN_EPS = 1e-5f;

constexpr int IC = 16;          // i-chunks in k_S (partial-sum slabs)
constexpr int ILEN = NI / IC;   // 32 i's per chunk
constexpr size_t SP_STRIDE = (size_t)NB * NK * NC;  // one Spart slab

// ---------------------------------------------------------------------------
// k_S: Spart[ic][b,k,c] = sum_{i in chunk} exp(z[b,i,k,c]) * (zmask[b,i,k]+1e-6)
// grid = NB*(NK/16)*IC = 2048 blocks, block = 256 (16 k x 16 float4-of-c).
// 4-deep manual unroll: 4 independent float4 loads + 4 accumulators in flight
// per thread (round-2 counters: VGPR=28, occ 40%, 2.4 TB/s -> MLP-starved).
// ---------------------------------------------------------------------------
__global__ __launch_bounds__(256) void k_S(const float* __restrict__ z,
                                           const float* __restrict__ zmask,
                                           float* __restrict__ Spart) {
    int idx = blockIdx.x;
    int ic = idx & (IC - 1); idx >>= 4;
    int kt = idx & 31; int b = idx >> 5;
    int tid = threadIdx.x;
    int kk = tid >> 4;              // 0..15
    int c4 = tid & 15;              // 0..15
    int k = kt * 16 + kk;

    float4 a0 = make_float4(0.f, 0.f, 0.f, 0.f);
    float4 a1 = a0, a2 = a0, a3 = a0;

    int i0 = ic * ILEN;
#pragma unroll 2
    for (int ii = 0; ii < ILEN; ii += 4) {
        size_t base = (size_t)(b * NI + i0 + ii) * NK + k;   // in mask elems
        const float4 z0 = *(const float4*)(z + (base         ) * NC + c4 * 4);
        const float4 z1 = *(const float4*)(z + (base +     NK) * NC + c4 * 4);
        const float4 z2 = *(const float4*)(z + (base + 2 * NK) * NC + c4 * 4);
        const float4 z3 = *(const float4*)(z + (base + 3 * NK) * NC + c4 * 4);
        float m0 = zmask[base         ] + 1e-6f;
        float m1 = zmask[base +     NK] + 1e-6f;
        float m2 = zmask[base + 2 * NK] + 1e-6f;
        float m3 = zmask[base + 3 * NK] + 1e-6f;
        a0.x += __expf(z0.x) * m0; a0.y += __expf(z0.y) * m0;
        a0.z += __expf(z0.z) * m0; a0.w += __expf(z0.w) * m0;
        a1.x += __expf(z1.x) * m1; a1.y += __expf(z1.y) * m1;
        a1.z += __expf(z1.z) * m1; a1.w += __expf(z1.w) * m1;
        a2.x += __expf(z2.x) * m2; a2.y += __expf(z2.y) * m2;
        a2.z += __expf(z2.z) * m2; a2.w += __expf(z2.w) * m2;
        a3.x += __expf(z3.x) * m3; a3.y += __expf(z3.y) * m3;
        a3.z += __expf(z3.z) * m3; a3.w += __expf(z3.w) * m3;
    }
    float4 acc;
    acc.x = (a0.x + a1.x) + (a2.x + a3.x);
    acc.y = (a0.y + a1.y) + (a2.y + a3.y);
    acc.z = (a0.z + a1.z) + (a2.z + a3.z);
    acc.w = (a0.w + a1.w) + (a2.w + a3.w);
    *(float4*)(Spart + (size_t)ic * SP_STRIDE + ((size_t)(b * NK) + k) * NC + c4 * 4) = acc;
}

// ---------------------------------------------------------------------------
// k_R: R[b,k,c] = (dot(Q[b,k,:], W1[c,:]) + b1[c]) / sum_ic Spart[ic][b,k,c]
// grid = NB*NK blocks of 64 threads (one per c)
// ---------------------------------------------------------------------------
__global__ __launch_bounds__(64) void k_R(const float* __restrict__ Q,
                                          const float* __restrict__ W1,
                                          const float* __restrict__ b1,
                                          const float* __restrict__ Spart,
                                          float* __restrict__ R) {
    int bk = blockIdx.x;
    int c = threadIdx.x;
    __shared__ float q[NC];
    q[c] = Q[(size_t)bk * NC + c];
    __syncthreads();
    const float* w = W1 + c * NC;
    float acc = b1[c];
#pragma unroll
    for (int j = 0; j < NC; ++j) acc += q[j] * w[j];
    float s = 0.f;
#pragma unroll
    for (int ic = 0; ic < IC; ++ic)
        s += Spart[(size_t)ic * SP_STRIDE + (size_t)bk * NC + c];
    R[(size_t)bk * NC + c] = acc / s;
}

// ---------------------------------------------------------------------------
// k_Va: Va[b,i,c] = sum_k mask*(mask+1e-6)*exp(z[b,i,k,c]) * R[b,k,c]
// grid = B*I blocks, block = 256 (16 k-stripes x 16 float4-of-c)
// 4-deep unroll, 4 independent accumulator sets (same MLP theory as k_S).
// Also emits per-(b,i) partial (sum, sumsq) for LN1.
// ---------------------------------------------------------------------------
__global__ __launch_bounds__(256) void k_Va(const float* __restrict__ z,
                                            const float* __restrict__ zmask,
                                            const float* __restrict__ R,
                                            float* __restrict__ Va,
                                            float* __restrict__ part1) {
    int bi = blockIdx.x;
    int b = bi >> 9;                 // / NI
    int tid = threadIdx.x;
    int kk = tid >> 4;
    int c4 = tid & 15;

    const float* zrow = z + (size_t)bi * NK * NC + c4 * 4;
    const float* mrow = zmask + (size_t)bi * NK;
    const float* Rb = R + (size_t)b * NK * NC + c4 * 4;

    float4 a0 = make_float4(0.f, 0.f, 0.f, 0.f);
    float4 a1 = a0, a2 = a0, a3 = a0;
#pragma unroll 2
    for (int kb = 0; kb < NK / 64; ++kb) {
        int k0 = kb * 64 + kk;
        const float4 z0 = *(const float4*)(zrow + (size_t)(k0     ) * NC);
        const float4 z1 = *(const float4*)(zrow + (size_t)(k0 + 16) * NC);
        const float4 z2 = *(const float4*)(zrow + (size_t)(k0 + 32) * NC);
        const float4 z3 = *(const float4*)(zrow + (size_t)(k0 + 48) * NC);
        const float4 r0 = *(const float4*)(Rb + (size_t)(k0     ) * NC);
        const float4 r1 = *(const float4*)(Rb + (size_t)(k0 + 16) * NC);
        const float4 r2 = *(const float4*)(Rb + (size_t)(k0 + 32) * NC);
        const float4 r3 = *(const float4*)(Rb + (size_t)(k0 + 48) * NC);
        float w0 = mrow[k0];      w0 = w0 * (w0 + 1e-6f);
        float w1 = mrow[k0 + 16]; w1 = w1 * (w1 + 1e-6f);
        float w2 = mrow[k0 + 32]; w2 = w2 * (w2 + 1e-6f);
        float w3 = mrow[k0 + 48]; w3 = w3 * (w3 + 1e-6f);
        a0.x += __expf(z0.x) * w0 * r0.x; a0.y += __expf(z0.y) * w0 * r0.y;
        a0.z += __expf(z0.z) * w0 * r0.z; a0.w += __expf(z0.w) * w0 * r0.w;
        a1.x += __expf(z1.x) * w1 * r1.x; a1.y += __expf(z1.y) * w1 * r1.y;
        a1.z += __expf(z1.z) * w1 * r1.z; a1.w += __expf(z1.w) * w1 * r1.w;
        a2.x += __expf(z2.x) * w2 * r2.x; a2.y += __expf(z2.y) * w2 * r2.y;
        a2.z += __expf(z2.z) * w2 * r2.z; a2.w += __expf(z2.w) * w2 * r2.w;
        a3.x += __expf(z3.x) * w3 * r3.x; a3.y += __expf(z3.y) * w3 * r3.y;
        a3.z += __expf(z3.z) * w3 * r3.z; a3.w += __expf(z3.w) * w3 * r3.w;
    }
    float4 acc;
    acc.x = (a0.x + a1.x) + (a2.x + a3.x);
    acc.y = (a0.y + a1.y) + (a2.y + a3.y);
    acc.z = (a0.z + a1.z) + (a2.z + a3.z);
    acc.w = (a0.w + a1.w) + (a2.w + a3.w);

    __shared__ float4 part[256];
    part[tid] = acc;
    __syncthreads();
    // reduce across the 16 kk-stripes (tid = kk*16 + c4)
    for (int s = 128; s >= 16; s >>= 1) {
        if (tid < s) {
            float4 o = part[tid + s];
            float4 m = part[tid];
            m.x += o.x; m.y += o.y; m.z += o.z; m.w += o.w;
            part[tid] = m;
        }
        __syncthreads();
    }
    __shared__ float red[32];
    if (tid < 16) {
        float4 v = part[tid];
        *(float4*)(Va + (size_t)bi * NC + tid * 4) = v;
        red[tid]      = v.x + v.y + v.z + v.w;
        red[16 + tid] = v.x * v.x + v.y * v.y + v.z * v.z + v.w * v.w;
    }
    __syncthreads();
    if (tid == 0) {
        float s0 = 0.f, s1 = 0.f;
        for (int t = 0; t < 16; ++t) { s0 += red[t]; s1 += red[16 + t]; }
        part1[bi * 2]     = s0;
        part1[bi * 2 + 1] = s1;
    }
}

// ---------------------------------------------------------------------------
// k_red: per-batch reduce of (sum, sumsq) partials -> stats[b*2], stats[b*2+1]
// grid = B, block = 256
// ---------------------------------------------------------------------------
__global__ __launch_bounds__(256) void k_red(const float* __restrict__ part,
                                             float* __restrict__ stats) {
    int b = blockIdx.x;
    int tid = threadIdx.x;
    float s0 = 0.f, s1 = 0.f;
    for (int i = tid; i < NI; i += 256) {
        int bi = b * NI + i;
        s0 += part[bi * 2];
        s1 += part[bi * 2 + 1];
    }
    __shared__ float l0[256], l1[256];
    l0[tid] = s0; l1[tid] = s1;
    __syncthreads();
    for (int s = 128; s; s >>= 1) {
        if (tid < s) { l0[tid] += l0[tid + s]; l1[tid] += l1[tid + s]; }
        __syncthreads();
    }
    if (tid == 0) { stats[b * 2] = l0[0]; stats[b * 2 + 1] = l1[0]; }
}

// ---------------------------------------------------------------------------
// k_Y: Y[b,i,c] = V + (LN1(Va) @ W2^T + b2); emits LN2 partials per (b,i)
// grid = B*I, block = 64 (one wave)
// ---------------------------------------------------------------------------
__global__ __launch_bounds__(64) void k_Y(const float* __restrict__ V,
                                          const float* __restrict__ W2,
                                          const float* __restrict__ b2,
                                          const float* __restrict__ Va,
                                          const float* __restrict__ stats1,
                                          float* __restrict__ Y,
                                          float* __restrict__ part2) {
    int bi = blockIdx.x;
    int b = bi >> 9;
    int c = threadIdx.x;
    const float n = (float)(NI * NC);
    float mu = stats1[b * 2] / n;
    float var = stats1[b * 2 + 1] / n - mu * mu;
    float rstd = rsqrtf(var + LN_EPS);

    __shared__ float xn[NC];
    xn[c] = (Va[(size_t)bi * NC + c] - mu) * rstd;
    __syncthreads();

    const float* w = W2 + c * NC;
    float acc = b2[c];
#pragma unroll
    for (int j = 0; j < NC; ++j) acc += xn[j] * w[j];
    float y = V[(size_t)bi * NC + c] + acc;
    Y[(size_t)bi * NC + c] = y;

    float s0 = y, s1 = y * y;
    for (int off = 32; off; off >>= 1) {
        s0 += __shfl_down(s0, off);
        s1 += __shfl_down(s1, off);
    }
    if (c == 0) { part2[bi * 2] = s0; part2[bi * 2 + 1] = s1; }
}

// ---------------------------------------------------------------------------
// k_out: out = LN2(Y), elementwise with per-b stats
// ---------------------------------------------------------------------------
__global__ __launch_bounds__(256) void k_out(const float* __restrict__ Y,
                                             const float* __restrict__ stats2,
                                             float* __restrict__ out) {
    int idx = blockIdx.x * 256 + threadIdx.x;
    int b = idx >> 15;               // / (NI*NC)
    const float n = (float)(NI * NC);
    float mu = stats2[b * 2] / n;
    float var = stats2[b * 2 + 1] / n - mu * mu;
    float rstd = rsqrtf(var + LN_EPS);
    out[idx] = (Y[idx] - mu) * rstd;
}

// ---------------------------------------------------------------------------
extern "C" void kernel_launch(void* const* d_in, const int* in_sizes, int n_in,
                              void* d_out, int out_size, void* d_ws, size_t ws_size,
                              hipStream_t stream) {
    const float* V  = (const float*)d_in[0];
    const float* Q  = (const float*)d_in[1];
    const float* z  = (const float*)d_in[2];
    const float* zm = (const float*)d_in[3];
    const float* W1 = (const float*)d_in[4];
    const float* b1 = (const float*)d_in[5];
    const float* W2 = (const float*)d_in[6];
    const float* b2 = (const float*)d_in[7];
    // d_in[8] is dim == 1 (fixed by setup_inputs)

    float* ws     = (float*)d_ws;
    float* Spart  = ws;                          // IC*NB*NK*NC = 2,097,152
    float* R      = ws + 2097152;                // 131072
    float* Va     = ws + 2228224;                // 131072
    float* Y      = ws + 2359296;                // 131072
    float* part1  = ws + 2490368;                // 4096
    float* part2  = ws + 2494464;                // 4096
    float* stats1 = ws + 2498560;                // 8
    float* stats2 = ws + 2498568;                // 8

    k_S  <<<NB * (NK / 16) * IC, 256, 0, stream>>>(z, zm, Spart);
    k_R  <<<NB * NK,             64,  0, stream>>>(Q, W1, b1, Spart, R);
    k_Va <<<NB * NI,             256, 0, stream>>>(z, zm, R, Va, part1);
    k_red<<<NB,                  256, 0, stream>>>(part1, stats1);
    k_Y  <<<NB * NI,             64,  0, stream>>>(V, W2, b2, Va, stats1, Y, part2);
    k_red<<<NB,                  256, 0, stream>>>(part2, stats2);
    k_out<<<(NB * NI * NC) / 256, 256, 0, stream>>>(Y, stats2, (float*)d_out);
}

// Round 4
// 408.658 us; speedup vs baseline: 1.5867x; 1.0783x over previous
//
#include <hip/hip_runtime.h>

// Problem constants (fixed by setup_inputs)
constexpr int NB = 4;
constexpr int NI = 512;
constexpr int NK = 512;
constexpr int NC = 64;
constexpr float LN_EPS = 1e-5f;

constexpr int IC = 16;          // i-chunks in k_S (partial-sum slabs)
constexpr int ILEN = NI / IC;   // 32 i's per chunk
constexpr size_t SP_STRIDE = (size_t)NB * NK * NC;  // one Spart slab

// ---------------------------------------------------------------------------
// k_S: Spart[ic][b,k,c] = sum_{i in chunk, zm!=0} exp(z[b,i,k,c])*(zm+1e-6)
// Mask-skip: rows with zm==0 contribute only 1e-6*exp(z) to S (rel ~4e-7,
// worst ~1e-4) and are DROPPED — their 256B z-rows are never fetched.
// Rounds 1/3 proved residency & MLP don't matter; cold reads cap ~2.45 TB/s,
// so bytes-read is the only lever. grid = NB*(NK/16)*IC = 2048, block = 256.
// ---------------------------------------------------------------------------
__global__ __launch_bounds__(256) void k_S(const float* __restrict__ z,
                                           const float* __restrict__ zmask,
                                           float* __restrict__ Spart) {
    int idx = blockIdx.x;
    int ic = idx & (IC - 1); idx >>= 4;
    int kt = idx & 31; int b = idx >> 5;
    int tid = threadIdx.x;
    int kk = tid >> 4;              // 0..15
    int c4 = tid & 15;              // 0..15
    int k = kt * 16 + kk;

    float4 a0 = make_float4(0.f, 0.f, 0.f, 0.f);
    float4 a1 = a0;

    int i0 = ic * ILEN;
    for (int ii = 0; ii < ILEN; ii += 2) {
        size_t base = (size_t)(b * NI + i0 + ii) * NK + k;   // in mask elems
        float m0 = zmask[base];
        float m1 = zmask[base + NK];
        if (m0 != 0.f) {
            const float4 z0 = *(const float4*)(z + base * NC + c4 * 4);
            float w = m0 + 1e-6f;
            a0.x += __expf(z0.x) * w;
            a0.y += __expf(z0.y) * w;
            a0.z += __expf(z0.z) * w;
            a0.w += __expf(z0.w) * w;
        }
        if (m1 != 0.f) {
            const float4 z1 = *(const float4*)(z + (base + NK) * NC + c4 * 4);
            float w = m1 + 1e-6f;
            a1.x += __expf(z1.x) * w;
            a1.y += __expf(z1.y) * w;
            a1.z += __expf(z1.z) * w;
            a1.w += __expf(z1.w) * w;
        }
    }
    float4 acc;
    acc.x = a0.x + a1.x;
    acc.y = a0.y + a1.y;
    acc.z = a0.z + a1.z;
    acc.w = a0.w + a1.w;
    *(float4*)(Spart + (size_t)ic * SP_STRIDE + ((size_t)(b * NK) + k) * NC + c4 * 4) = acc;
}

// ---------------------------------------------------------------------------
// k_R: R[b,k,c] = (dot(Q[b,k,:], W1[c,:]) + b1[c]) / sum_ic Spart[ic][b,k,c]
// grid = NB*NK blocks of 64 threads (one per c).
// Note: if ALL i are masked for (b,k), S==0 -> R=inf; harmless because every
// pass-2 consumer of that (b,k) is itself mask-skipped.
// ---------------------------------------------------------------------------
__global__ __launch_bounds__(64) void k_R(const float* __restrict__ Q,
                                          const float* __restrict__ W1,
                                          const float* __restrict__ b1,
                                          const float* __restrict__ Spart,
                                          float* __restrict__ R) {
    int bk = blockIdx.x;
    int c = threadIdx.x;
    __shared__ float q[NC];
    q[c] = Q[(size_t)bk * NC + c];
    __syncthreads();
    const float* w = W1 + c * NC;
    float acc = b1[c];
#pragma unroll
    for (int j = 0; j < NC; ++j) acc += q[j] * w[j];
    float s = 0.f;
#pragma unroll
    for (int ic = 0; ic < IC; ++ic)
        s += Spart[(size_t)ic * SP_STRIDE + (size_t)bk * NC + c];
    R[(size_t)bk * NC + c] = acc / s;
}

// ---------------------------------------------------------------------------
// k_Va: Va[b,i,c] = sum_{k, zm!=0} exp(z[b,i,k,c]) * zm*(zm+1e-6) * R[b,k,c]
// Mask-skip here is EXACT: zm==0 => m2==0 => term==0. Skipped rows fetch no
// z bytes and no R. grid = B*I blocks, block = 256 (16 k x 16 float4-of-c).
// Also emits per-(b,i) partial (sum, sumsq) for LN1.
// ---------------------------------------------------------------------------
__global__ __launch_bounds__(256) void k_Va(const float* __restrict__ z,
                                            const float* __restrict__ zmask,
                                            const float* __restrict__ R,
                                            float* __restrict__ Va,
                                            float* __restrict__ part1) {
    int bi = blockIdx.x;
    int b = bi >> 9;                 // / NI
    int tid = threadIdx.x;
    int kk = tid >> 4;
    int c4 = tid & 15;

    const float* zrow = z + (size_t)bi * NK * NC + c4 * 4;
    const float* mrow = zmask + (size_t)bi * NK;
    const float* Rb = R + (size_t)b * NK * NC + c4 * 4;

    float4 a0 = make_float4(0.f, 0.f, 0.f, 0.f);
    float4 a1 = a0;
    for (int kb = 0; kb < NK / 32; ++kb) {
        int k0 = kb * 32 + kk;
        float m0 = mrow[k0];
        float m1 = mrow[k0 + 16];
        if (m0 != 0.f) {
            const float4 zv = *(const float4*)(zrow + (size_t)k0 * NC);
            const float4 rv = *(const float4*)(Rb + (size_t)k0 * NC);
            float w = m0 * (m0 + 1e-6f);
            a0.x += __expf(zv.x) * w * rv.x;
            a0.y += __expf(zv.y) * w * rv.y;
            a0.z += __expf(zv.z) * w * rv.z;
            a0.w += __expf(zv.w) * w * rv.w;
        }
        if (m1 != 0.f) {
            const float4 zv = *(const float4*)(zrow + (size_t)(k0 + 16) * NC);
            const float4 rv = *(const float4*)(Rb + (size_t)(k0 + 16) * NC);
            float w = m1 * (m1 + 1e-6f);
            a1.x += __expf(zv.x) * w * rv.x;
            a1.y += __expf(zv.y) * w * rv.y;
            a1.z += __expf(zv.z) * w * rv.z;
            a1.w += __expf(zv.w) * w * rv.w;
        }
    }
    float4 acc;
    acc.x = a0.x + a1.x;
    acc.y = a0.y + a1.y;
    acc.z = a0.z + a1.z;
    acc.w = a0.w + a1.w;

    __shared__ float4 part[256];
    part[tid] = acc;
    __syncthreads();
    // reduce across the 16 kk-stripes (tid = kk*16 + c4)
    for (int s = 128; s >= 16; s >>= 1) {
        if (tid < s) {
            float4 o = part[tid + s];
            float4 m = part[tid];
            m.x += o.x; m.y += o.y; m.z += o.z; m.w += o.w;
            part[tid] = m;
        }
        __syncthreads();
    }
    __shared__ float red[32];
    if (tid < 16) {
        float4 v = part[tid];
        *(float4*)(Va + (size_t)bi * NC + tid * 4) = v;
        red[tid]      = v.x + v.y + v.z + v.w;
        red[16 + tid] = v.x * v.x + v.y * v.y + v.z * v.z + v.w * v.w;
    }
    __syncthreads();
    if (tid == 0) {
        float s0 = 0.f, s1 = 0.f;
        for (int t = 0; t < 16; ++t) { s0 += red[t]; s1 += red[16 + t]; }
        part1[bi * 2]     = s0;
        part1[bi * 2 + 1] = s1;
    }
}

// ---------------------------------------------------------------------------
// k_red: per-batch reduce of (sum, sumsq) partials -> stats[b*2], stats[b*2+1]
// grid = B, block = 256
// ---------------------------------------------------------------------------
__global__ __launch_bounds__(256) void k_red(const float* __restrict__ part,
                                             float* __restrict__ stats) {
    int b = blockIdx.x;
    int tid = threadIdx.x;
    float s0 = 0.f, s1 = 0.f;
    for (int i = tid; i < NI; i += 256) {
        int bi = b * NI + i;
        s0 += part[bi * 2];
        s1 += part[bi * 2 + 1];
    }
    __shared__ float l0[256], l1[256];
    l0[tid] = s0; l1[tid] = s1;
    __syncthreads();
    for (int s = 128; s; s >>= 1) {
        if (tid < s) { l0[tid] += l0[tid + s]; l1[tid] += l1[tid + s]; }
        __syncthreads();
    }
    if (tid == 0) { stats[b * 2] = l0[0]; stats[b * 2 + 1] = l1[0]; }
}

// ---------------------------------------------------------------------------
// k_Y: Y[b,i,c] = V + (LN1(Va) @ W2^T + b2); emits LN2 partials per (b,i)
// grid = B*I, block = 64 (one wave)
// ---------------------------------------------------------------------------
__global__ __launch_bounds__(64) void k_Y(const float* __restrict__ V,
                                          const float* __restrict__ W2,
                                          const float* __restrict__ b2,
                                          const float* __restrict__ Va,
                                          const float* __restrict__ stats1,
                                          float* __restrict__ Y,
                                          float* __restrict__ part2) {
    int bi = blockIdx.x;
    int b = bi >> 9;
    int c = threadIdx.x;
    const float n = (float)(NI * NC);
    float mu = stats1[b * 2] / n;
    float var = stats1[b * 2 + 1] / n - mu * mu;
    float rstd = rsqrtf(var + LN_EPS);

    __shared__ float xn[NC];
    xn[c] = (Va[(size_t)bi * NC + c] - mu) * rstd;
    __syncthreads();

    const float* w = W2 + c * NC;
    float acc = b2[c];
#pragma unroll
    for (int j = 0; j < NC; ++j) acc += xn[j] * w[j];
    float y = V[(size_t)bi * NC + c] + acc;
    Y[(size_t)bi * NC + c] = y;

    float s0 = y, s1 = y * y;
    for (int off = 32; off; off >>= 1) {
        s0 += __shfl_down(s0, off);
        s1 += __shfl_down(s1, off);
    }
    if (c == 0) { part2[bi * 2] = s0; part2[bi * 2 + 1] = s1; }
}

// ---------------------------------------------------------------------------
// k_out: out = LN2(Y), elementwise with per-b stats
// ---------------------------------------------------------------------------
__global__ __launch_bounds__(256) void k_out(const float* __restrict__ Y,
                                             const float* __restrict__ stats2,
                                             float* __restrict__ out) {
    int idx = blockIdx.x * 256 + threadIdx.x;
    int b = idx >> 15;               // / (NI*NC)
    const float n = (float)(NI * NC);
    float mu = stats2[b * 2] / n;
    float var = stats2[b * 2 + 1] / n - mu * mu;
    float rstd = rsqrtf(var + LN_EPS);
    out[idx] = (Y[idx] - mu) * rstd;
}

// ---------------------------------------------------------------------------
extern "C" void kernel_launch(void* const* d_in, const int* in_sizes, int n_in,
                              void* d_out, int out_size, void* d_ws, size_t ws_size,
                              hipStream_t stream) {
    const float* V  = (const float*)d_in[0];
    const float* Q  = (const float*)d_in[1];
    const float* z  = (const float*)d_in[2];
    const float* zm = (const float*)d_in[3];
    const float* W1 = (const float*)d_in[4];
    const float* b1 = (const float*)d_in[5];
    const float* W2 = (const float*)d_in[6];
    const float* b2 = (const float*)d_in[7];
    // d_in[8] is dim == 1 (fixed by setup_inputs)

    float* ws     = (float*)d_ws;
    float* Spart  = ws;                          // IC*NB*NK*NC = 2,097,152
    float* R      = ws + 2097152;                // 131072
    float* Va     = ws + 2228224;                // 131072
    float* Y      = ws + 2359296;                // 131072
    float* part1  = ws + 2490368;                // 4096
    float* part2  = ws + 2494464;                // 4096
    float* stats1 = ws + 2498560;                // 8
    float* stats2 = ws + 2498568;                // 8

    k_S  <<<NB * (NK / 16) * IC, 256, 0, stream>>>(z, zm, Spart);
    k_R  <<<NB * NK,             64,  0, stream>>>(Q, W1, b1, Spart, R);
    k_Va <<<NB * NI,             256, 0, stream>>>(z, zm, R, Va, part1);
    k_red<<<NB,                  256, 0, stream>>>(part1, stats1);
    k_Y  <<<NB * NI,             64,  0, stream>>>(V, W2, b2, Va, stats1, Y, part2);
    k_red<<<NB,                  256, 0, stream>>>(part2, stats2);
    k_out<<<(NB * NI * NC) / 256, 256, 0, stream>>>(Y, stats2, (float*)d_out);
}